// Round 1
// baseline (132.663 us; speedup 1.0000x reference)
//
#include <hip/hip_runtime.h>

#define N_ATOMS 10000
#define N_DIH   8000
#define NB      2048          // frames (innermost, contiguous)
#define EPS     1e-12f

// One thread = one dihedral x 4 consecutive frames (float4 lanes).
// threads-per-dihedral = NB/4 = 512; block = 256 -> each block touches
// exactly one dihedral (4 atom rows) => great gather locality.
__global__ __launch_bounds__(256) void dihedral_kernel(
    const float* __restrict__ x,      // (N_ATOMS, 3, NB)
    const int*   __restrict__ atoms,  // (N_DIH, 4)
    float*       __restrict__ out)    // (2*N_DIH, NB)
{
    const int t  = blockIdx.x * 256 + threadIdx.x;
    const int d  = t >> 9;            // / (NB/4)
    const int bq = t & 511;           // % (NB/4)
    const int b  = bq << 2;           // frame base
    if (d >= N_DIH) return;

    const int4 aidx = *reinterpret_cast<const int4*>(atoms + d * 4);
    const int ai[4] = {aidx.x, aidx.y, aidx.z, aidx.w};

    // g[atom][coord] : 4 frames packed in a float4
    float4 g[4][3];
#pragma unroll
    for (int j = 0; j < 4; ++j) {
        const float* base = x + (size_t)ai[j] * (3 * NB) + b;
#pragma unroll
        for (int c = 0; c < 3; ++c) {
            g[j][c] = *reinterpret_cast<const float4*>(base + c * NB);
        }
    }

    float o0[4], o1[4];
#pragma unroll
    for (int k = 0; k < 4; ++k) {
        float p[4][3];
#pragma unroll
        for (int j = 0; j < 4; ++j) {
            p[j][0] = reinterpret_cast<const float*>(&g[j][0])[k];
            p[j][1] = reinterpret_cast<const float*>(&g[j][1])[k];
            p[j][2] = reinterpret_cast<const float*>(&g[j][2])[k];
        }

        float a12[3], a23[3], a34[3];
#pragma unroll
        for (int c = 0; c < 3; ++c) {
            a12[c] = p[1][c] - p[0][c];
            a23[c] = p[2][c] - p[1][c];
            a34[c] = p[3][c] - p[2][c];
        }
        // normalize (match reference: v / max(|v|, eps))
        {
            float n12 = sqrtf(a12[0]*a12[0] + a12[1]*a12[1] + a12[2]*a12[2]);
            float n23 = sqrtf(a23[0]*a23[0] + a23[1]*a23[1] + a23[2]*a23[2]);
            float n34 = sqrtf(a34[0]*a34[0] + a34[1]*a34[1] + a34[2]*a34[2]);
            float i12 = 1.0f / fmaxf(n12, EPS);
            float i23 = 1.0f / fmaxf(n23, EPS);
            float i34 = 1.0f / fmaxf(n34, EPS);
#pragma unroll
            for (int c = 0; c < 3; ++c) { a12[c] *= i12; a23[c] *= i23; a34[c] *= i34; }
        }

        // vp1 = a12 x a23 ; vp2 = a23 x a34 ; vp3 = vp1 x a23
        float vp1[3], vp2[3], vp3[3];
        vp1[0] = a12[1]*a23[2] - a12[2]*a23[1];
        vp1[1] = a12[2]*a23[0] - a12[0]*a23[2];
        vp1[2] = a12[0]*a23[1] - a12[1]*a23[0];

        vp2[0] = a23[1]*a34[2] - a23[2]*a34[1];
        vp2[1] = a23[2]*a34[0] - a23[0]*a34[2];
        vp2[2] = a23[0]*a34[1] - a23[1]*a34[0];

        vp3[0] = vp1[1]*a23[2] - vp1[2]*a23[1];
        vp3[1] = vp1[2]*a23[0] - vp1[0]*a23[2];
        vp3[2] = vp1[0]*a23[1] - vp1[1]*a23[0];

        float sp1 = vp1[0]*vp2[0] + vp1[1]*vp2[1] + vp1[2]*vp2[2];
        float sp2 = vp3[0]*vp2[0] + vp3[1]*vp2[1] + vp3[2]*vp2[2];

        float nrm  = sqrtf(sp1*sp1 + sp2*sp2);
        float inv  = 1.0f / fmaxf(nrm, EPS);
        o0[k] = -sp2 * inv;   // st[0]
        o1[k] =  sp1 * inv;   // st[1]
    }

    float4 v0 = make_float4(o0[0], o0[1], o0[2], o0[3]);
    float4 v1 = make_float4(o1[0], o1[1], o1[2], o1[3]);
    *reinterpret_cast<float4*>(out + (size_t)d * NB + b)            = v0;
    *reinterpret_cast<float4*>(out + (size_t)(N_DIH + d) * NB + b)  = v1;
}

extern "C" void kernel_launch(void* const* d_in, const int* in_sizes, int n_in,
                              void* d_out, int out_size, void* d_ws, size_t ws_size,
                              hipStream_t stream) {
    const float* x     = (const float*)d_in[0];
    const int*   atoms = (const int*)d_in[1];
    float*       out   = (float*)d_out;

    const int total   = N_DIH * (NB / 4);   // 4,096,000 threads
    const int block   = 256;
    const int grid    = total / block;      // 16000 blocks
    dihedral_kernel<<<grid, block, 0, stream>>>(x, atoms, out);
}